// Round 11
// baseline (291.003 us; speedup 1.0000x reference)
//
#include <hip/hip_runtime.h>
#include <hip/hip_bf16.h>

// ---- constants for this problem ----
#define BB 4
#define TT 2048
#define C_IN 1152
#define NE 1024
#define NH 16
#define HD 64
#define MM (BB*TT)          // 8192
#define N_QKV (3*NE)        // 3072

typedef __attribute__((ext_vector_type(8))) short s16x8;
typedef __attribute__((ext_vector_type(4))) short s16x4;
typedef __attribute__((ext_vector_type(4))) float f32x4;

static __device__ __forceinline__ unsigned short f2bf(float x) {
    unsigned int u = __float_as_uint(x);
    unsigned int r = (u + 0x7fffu + ((u >> 16) & 1u)) >> 16;
    return (unsigned short)r;
}

// async global->LDS, 16 B per lane. LDS dest = wave-uniform base + lane*16.
static __device__ __forceinline__ void async16(const void* g, void* l) {
    __builtin_amdgcn_global_load_lds((const __attribute__((address_space(1))) void*)g,
                                     (__attribute__((address_space(3))) void*)l, 16, 0, 0);
}

// ---- prep kernel: LN (blocks 0..MM-1) + both weight transposes (rest) ----
// Fuses 3 launches into 1. Branches are whole-block uniform.
#define TCA_BLOCKS ((N_QKV / 32) * (C_IN / 32))   /* 3456 */
#define TCP_BLOCKS ((NE / 32) * (NE / 32))        /* 1024 */
__global__ __launch_bounds__(256) void prep_kernel(const float* __restrict__ x,
                                                   const float* __restrict__ lw,
                                                   const float* __restrict__ lb,
                                                   unsigned short* __restrict__ h,
                                                   const float* __restrict__ Wa,
                                                   unsigned short* __restrict__ Wat,
                                                   const float* __restrict__ Wp,
                                                   unsigned short* __restrict__ Wpt) {
    __shared__ float tile[32][33];
    __shared__ float red[2][4];
    const int bid = blockIdx.x;
    const int tid = threadIdx.x;

    if (bid < MM) {
        // ---- LayerNorm row (float4 loads, registers kept, bf16x4 stores) ----
        const float4* xr = (const float4*)(x + (size_t)bid * C_IN);   // 288 float4
        const float4 a0 = xr[tid];
        float4 a1 = make_float4(0.f, 0.f, 0.f, 0.f);
        if (tid < 32) a1 = xr[256 + tid];
        float s  = a0.x + a0.y + a0.z + a0.w + a1.x + a1.y + a1.z + a1.w;
        float sq = a0.x*a0.x + a0.y*a0.y + a0.z*a0.z + a0.w*a0.w
                 + a1.x*a1.x + a1.y*a1.y + a1.z*a1.z + a1.w*a1.w;
        for (int off = 1; off < 64; off <<= 1) {
            s  += __shfl_xor(s, off, 64);
            sq += __shfl_xor(sq, off, 64);
        }
        const int wid = tid >> 6, lane = tid & 63;
        if (lane == 0) { red[0][wid] = s; red[1][wid] = sq; }
        __syncthreads();
        s  = red[0][0] + red[0][1] + red[0][2] + red[0][3];
        sq = red[1][0] + red[1][1] + red[1][2] + red[1][3];
        const float mu  = s * (1.f / C_IN);
        const float var = sq * (1.f / C_IN) - mu * mu;
        const float rs  = rsqrtf(var + 1e-5f);
        const float4* w4 = (const float4*)lw;
        const float4* b4 = (const float4*)lb;
        unsigned short* hr = h + (size_t)bid * C_IN;
        {
            const float4 wv = w4[tid], bv = b4[tid];
            s16x4 o;
            o[0] = (short)f2bf((a0.x - mu) * rs * wv.x + bv.x);
            o[1] = (short)f2bf((a0.y - mu) * rs * wv.y + bv.y);
            o[2] = (short)f2bf((a0.z - mu) * rs * wv.z + bv.z);
            o[3] = (short)f2bf((a0.w - mu) * rs * wv.w + bv.w);
            *(s16x4*)(hr + tid * 4) = o;
        }
        if (tid < 32) {
            const float4 wv = w4[256 + tid], bv = b4[256 + tid];
            s16x4 o;
            o[0] = (short)f2bf((a1.x - mu) * rs * wv.x + bv.x);
            o[1] = (short)f2bf((a1.y - mu) * rs * wv.y + bv.y);
            o[2] = (short)f2bf((a1.z - mu) * rs * wv.z + bv.z);
            o[3] = (short)f2bf((a1.w - mu) * rs * wv.w + bv.w);
            *(s16x4*)(hr + (256 + tid) * 4) = o;
        }
        return;
    }

    // ---- transpose+cast tile ----
    const float* in; unsigned short* out; int K, N, n0, k0;
    if (bid < MM + TCA_BLOCKS) {
        const int idx = bid - MM;
        in = Wa; out = Wat; K = C_IN; N = N_QKV;
        n0 = (idx % (N_QKV / 32)) * 32; k0 = (idx / (N_QKV / 32)) * 32;
    } else {
        const int idx = bid - MM - TCA_BLOCKS;
        in = Wp; out = Wpt; K = NE; N = NE;
        n0 = (idx % (NE / 32)) * 32; k0 = (idx / (NE / 32)) * 32;
    }
    const int tx = tid & 31, ty = tid >> 5;   // 32 x 8
    for (int i = ty; i < 32; i += 8)
        tile[i][tx] = in[(size_t)(k0 + i) * N + n0 + tx];
    __syncthreads();
    for (int i = ty; i < 32; i += 8)
        out[(size_t)(n0 + i) * K + k0 + tx] = f2bf(tile[tx][i]);
}

#define ATT_SC 0.18033688011112042f   /* (1/8) * log2(e) */

// ------------- GEMM: A bf16 [M][K] x Bt bf16 [N][K] + bias -> epilogue -------------
// Round-8 proven K-loop: BK=64, XOR-swizzled 128-B LDS rows.
// Round-9: MODE-0 L2-local 2D sub-tiled work order; single-stage MODE-0 epilogue.
#define EP_STRIDE 136   /* ushort; 272 B rows keep 16 B alignment for b128 */
template <int MODE>
__global__ __launch_bounds__(256) void gemm_bt(const unsigned short* __restrict__ A,
                                               const unsigned short* __restrict__ Bt,
                                               const float* __restrict__ bias,
                                               void* __restrict__ outp,
                                               unsigned short* __restrict__ kb,
                                               unsigned short* __restrict__ vt,
                                               int M, int N, int K) {
    __shared__ unsigned short smem[32768];   // 64 KB: [2 buf][ A 8192 | B 8192 ]
    const int tid = threadIdx.x;
    const int wid = tid >> 6, lane = tid & 63;
    const int wm = wid >> 1, wn = wid & 1;
    const int quad = lane >> 4, l16 = lane & 15;

    int m0, n0;
    if (MODE == 0) {
        // 2D sub-tiled XCD-local order: grid (24,64)=1536, 192 wg per XCD.
        const int bid = blockIdx.y * gridDim.x + blockIdx.x;
        const int xcd = bid & 7;
        const int k   = bid >> 3;          // 0..191
        const int mg  = k / 96;            // 0..1
        const int r1  = k % 96;
        const int ng  = r1 / 32;           // 0..2
        const int rr  = r1 % 32;
        m0 = (xcd * 8 + mg * 4 + (rr & 3)) * 128;
        n0 = (ng * 8 + (rr >> 2)) * 128;
    } else {
        // T1 bijective XCD-chunked swizzle (nwg % 8 == 0)
        const int gx  = gridDim.x;
        const int nwg = gx * gridDim.y;
        const int bid = blockIdx.y * gx + blockIdx.x;
        const int wg  = (bid & 7) * (nwg >> 3) + (bid >> 3);
        m0 = (wg / gx) * 128; n0 = (wg % gx) * 128;
    }

    const int rl = lane >> 3;                     // 0..7
    const int sc = (lane & 7) ^ rl;               // stored chunk index
    const unsigned short* gA = A  + (size_t)(m0 + wid * 32 + rl) * K + sc * 8;
    const unsigned short* gB = Bt + (size_t)(n0 + wid * 32 + rl) * K + sc * 8;

    f32x4 acc[4][4] = {};
    const int nk = K >> 6;

    const int sc0 = (quad ^ (l16 & 7)) * 8;
    const int sc1 = ((4 + quad) ^ (l16 & 7)) * 8;

#define STAGE(KT, BUF)                                                          \
    {                                                                           \
        const unsigned short* a_ = gA + (KT) * 64;                              \
        const unsigned short* b_ = gB + (KT) * 64;                              \
        unsigned short* sa_ = &smem[(BUF) * 16384 + wid * 2048];                \
        unsigned short* sb_ = &smem[(BUF) * 16384 + 8192 + wid * 2048];         \
        _Pragma("unroll")                                                       \
        for (int j = 0; j < 4; j++) {                                           \
            async16(a_ + (size_t)(j * 8) * K, sa_ + j * 512);                   \
            async16(b_ + (size_t)(j * 8) * K, sb_ + j * 512);                   \
        }                                                                       \
    }

    STAGE(0, 0);

    for (int kt = 0; kt < nk; kt++) {
        __syncthreads();
        const int cur = kt & 1;
        if (kt + 1 < nk) STAGE(kt + 1, cur ^ 1);

        const unsigned short* As_ = &smem[cur * 16384];
        const unsigned short* Bs_ = &smem[cur * 16384 + 8192];
        #pragma unroll
        for (int h = 0; h < 2; h++) {
            const int sch = h ? sc1 : sc0;
            s16x8 af[4], bfb[4];
            #pragma unroll
            for (int mi = 0; mi < 4; mi++)
                af[mi] = *(const s16x8*)&As_[(wm * 64 + mi * 16 + l16) * 64 + sch];
            #pragma unroll
            for (int ni = 0; ni < 4; ni++)
                bfb[ni] = *(const s16x8*)&Bs_[(wn * 64 + ni * 16 + l16) * 64 + sch];
            #pragma unroll
            for (int mi = 0; mi < 4; mi++)
                #pragma unroll
                for (int ni = 0; ni < 4; ni++)
                    acc[mi][ni] = __builtin_amdgcn_mfma_f32_16x16x32_bf16(af[mi], bfb[ni], acc[mi][ni], 0, 0, 0);
        }
    }
#undef STAGE

    const int which0 = n0 >> 10;
    const float sc_ = (MODE == 0 && which0 == 0) ? ATT_SC : 1.0f;
    for (int ni = 0; ni < 4; ni++) {
        const float bv = bias[n0 + wn * 64 + ni * 16 + l16];
        for (int mi = 0; mi < 4; mi++)
            for (int r = 0; r < 4; r++)
                acc[mi][ni][r] = (acc[mi][ni][r] + bv) * sc_;
    }

    if (MODE == 1) {
        float* Tf = (float*)smem;
        float* out = (float*)outp;
        for (int p = 0; p < 2; p++) {
            __syncthreads();
            if (wm == p) {
                for (int mi = 0; mi < 4; mi++)
                    for (int ni = 0; ni < 4; ni++) {
                        const int col = wn * 64 + ni * 16 + l16;
                        for (int r = 0; r < 4; r++)
                            Tf[(mi * 16 + quad * 4 + r) * 128 + col] = acc[mi][ni][r];
                    }
            }
            __syncthreads();
            const int rlo = tid >> 5;
            const int c4 = (tid & 31) * 4;
            for (int rr2 = rlo; rr2 < 64; rr2 += 8) {
                *(float4*)&out[(size_t)(m0 + p * 64 + rr2) * N + n0 + c4] =
                    *(const float4*)&Tf[rr2 * 128 + c4];
            }
        }
        return;
    }

    // ---- MODE 0: single-stage LDS-routed epilogue (T [128][EP_STRIDE]) ----
    const int which = n0 >> 10;
    const int bb = m0 >> 11;
    const int mloc = m0 & 2047;
    unsigned short* T = smem;

    __syncthreads();
    if (which < 2) {
        for (int mi = 0; mi < 4; mi++)
            for (int ni = 0; ni < 4; ni++) {
                const int nl = wn * 64 + ni * 16 + l16;
                for (int r = 0; r < 4; r++)
                    T[(wm * 64 + mi * 16 + quad * 4 + r) * EP_STRIDE + nl] = f2bf(acc[mi][ni][r]);
            }
    } else {
        for (int mi = 0; mi < 4; mi++)
            for (int ni = 0; ni < 4; ni++) {
                const int nlh = wn * 64 + ni * 16 + l16;
                const int mlb = wm * 64 + mi * 16 + quad * 4;
                for (int r = 0; r < 4; r += 2) {
                    const unsigned int pk = (unsigned int)f2bf(acc[mi][ni][r]) |
                                            ((unsigned int)f2bf(acc[mi][ni][r + 1]) << 16);
                    *(unsigned int*)&T[nlh * EP_STRIDE + mlb + r] = pk;
                }
            }
    }
    __syncthreads();

    if (which < 2) {
        unsigned short* qk = (which == 0) ? (unsigned short*)outp : kb;
        const int ml = tid >> 2, c = tid & 3;
        const int nl0 = c * 32;
        const int hh = ((n0 & 1023) >> 6) + (nl0 >> 6);
        const int d0 = nl0 & 63;
        for (int half = 0; half < 2; half++) {
            const int row = half * 64 + ml;
            const int t = mloc + row;
            unsigned short* dst = qk + ((size_t)(bb * 16 + hh) * TT + t) * HD + d0;
            const unsigned short* src = &T[row * EP_STRIDE + nl0];
            for (int u = 0; u < 4; u++)
                *(s16x8*)(dst + u * 8) = *(const s16x8*)(src + u * 8);
        }
    } else {
        const int nlh = tid >> 2, c = tid & 3;
        const int hb = (n0 - 2048) >> 6;
        for (int half = 0; half < 2; half++) {
            const int row = half * 64 + nlh;
            unsigned short* dst = vt + ((size_t)(bb * 16 + hb + half) * HD + nlh) * TT + mloc + c * 32;
            const unsigned short* src = &T[row * EP_STRIDE + c * 32];
            for (int u = 0; u < 4; u++)
                *(s16x8*)(dst + u * 8) = *(const s16x8*)(src + u * 8);
        }
    }
}

// ------------- flash attention: S^T trick + ones-MFMA row sums -------------
// Round-9 proven version (best measured: 81.4 us): 4-wave 256-thread blocks,
// round-0 schedule (2-buffer __syncthreads staging, XOR-swizzled K/V),
// diag-hoisted causal mask, setprio(1) around the rowsum+PV MFMA cluster.
// (Round-10's 8-wave variant regressed: LDS 69.6KB still capped at 2 blocks/CU,
// so no occupancy gain, and the wider 8-wave barrier amplified wave imbalance.)
#define PST 72                         /* shorts; 144 B rows, 16B-aligned */

__global__ __launch_bounds__(256) void attn_kernel(const unsigned short* __restrict__ qb,
                                                   const unsigned short* __restrict__ kb,
                                                   const unsigned short* __restrict__ vt,
                                                   unsigned short* __restrict__ yb) {
    __shared__ unsigned short Ks[2][64 * 64];
    __shared__ unsigned short Vs[2][64 * 64];
    __shared__ unsigned short Ps[4][2 * 16 * PST];   // per-wave, per-mf [16 q][PST]
    const int tid = threadIdx.x, wid = tid >> 6, lane = tid & 63;
    const int quad = lane >> 4, l16 = lane & 15;
    const int bh = blockIdx.x & 63;
    const int qblk = 15 - (blockIdx.x >> 6);         // longest-first (LPT packing)

    const unsigned short* qh = qb + (size_t)bh * TT * HD;
    const unsigned short* kh = kb + (size_t)bh * TT * HD;
    const unsigned short* vh = vt + (size_t)bh * HD * TT;
    unsigned short* ps = Ps[wid];

    const int q0w = qblk * 128 + wid * 32;           // this wave's 32 q-rows
    s16x8 aq[2][2];
    #pragma unroll
    for (int mf = 0; mf < 2; mf++) {
        aq[mf][0] = *(const s16x8*)&qh[(size_t)(q0w + mf * 16 + l16) * HD + quad * 8];
        aq[mf][1] = *(const s16x8*)&qh[(size_t)(q0w + mf * 16 + l16) * HD + 32 + quad * 8];
    }
    // ones B-frag (bf16 1.0 = 0x3F80)
    s16x8 onesf;
    #pragma unroll
    for (int i = 0; i < 8; i++) onesf[i] = (short)0x3F80;

    f32x4 yacc[2][4] = {};
    f32x4 lacc[2] = {};                              // row-sum accumulators
    const int ntiles = 2 * qblk + 2;                 // always even

    // staging: row r = wid*16 + {0,8} + rl, chunk cc XOR-swizzled; pointers bumped
    const int rl = lane >> 3;
    const int cc = (lane & 7) ^ (rl & 7);
    const unsigned short* kp0 = kh + (size_t)(wid * 16 + rl) * HD + cc * 8;
    const unsigned short* kp1 = kh + (size_t)(wid * 16 + 8 + rl) * HD + cc * 8;
    const unsigned short* vp0 = vh + (size_t)(wid * 16 + rl) * TT + cc * 8;
    const unsigned short* vp1 = vh + (size_t)(wid * 16 + 8 + rl) * TT + cc * 8;
    const int ldsK0 = wid * 16 * 64, ldsK1 = (wid * 16 + 8) * 64;

    // prologue: stage tile 0 into buffer 0; bump to tile 1
    async16(kp0, &Ks[0][ldsK0]);  async16(kp1, &Ks[0][ldsK1]);
    async16(vp0, &Vs[0][ldsK0]);  async16(vp1, &Vs[0][ldsK1]);
    kp0 += 64 * HD; kp1 += 64 * HD; vp0 += 64; vp1 += 64;

    const int p0s = quad ^ (l16 & 7);
    const int p1s = (4 + quad) ^ (l16 & 7);

#define ATT_STEP(CUR, TT_)                                                              \
    {                                                                                   \
        __syncthreads();                                                                \
        if ((TT_) + 1 < ntiles) {                                                       \
            async16(kp0, &Ks[(CUR) ^ 1][ldsK0]);  async16(kp1, &Ks[(CUR) ^ 1][ldsK1]);  \
            async16(vp0, &Vs[(CUR) ^ 1][ldsK0]);  async16(vp1, &Vs[(CUR) ^ 1][ldsK1]);  \
            kp0 += 64 * HD; kp1 += 64 * HD; vp0 += 64; vp1 += 64;                       \
        }                                                                               \
        const int tk0 = (TT_) * 64;                                                     \
        if (tk0 <= q0w + 31) {                                                          \
            const unsigned short* Kc = Ks[CUR];                                         \
            const unsigned short* Vc = Vs[CUR];                                         \
            s16x8 kf[4][2], vf[4][2];                                                   \
            _Pragma("unroll")                                                           \
            for (int nj = 0; nj < 4; nj++) {                                            \
                kf[nj][0] = *(const s16x8*)&Kc[(nj * 16 + l16) * 64 + p0s * 8];         \
                kf[nj][1] = *(const s16x8*)&Kc[(nj * 16 + l16) * 64 + p1s * 8];         \
            }                                                                           \
            _Pragma("unroll")                                                           \
            for (int ni = 0; ni < 4; ni++) {                                            \
                vf[ni][0] = *(const s16x8*)&Vc[(ni * 16 + l16) * 64 + p0s * 8];         \
                vf[ni][1] = *(const s16x8*)&Vc[(ni * 16 + l16) * 64 + p1s * 8];         \
            }                                                                           \
            _Pragma("unroll")                                                           \
            for (int mf = 0; mf < 2; mf++) {                                            \
                const int f0 = q0w + mf * 16;                                           \
                if (tk0 > f0 + 15) continue;                                            \
                unsigned short* pm = ps + mf * (16 * PST);                              \
                const int qg = f0 + l16;                                                \
                f32x4 st[4];                                                            \
                _Pragma("unroll")                                                       \
                for (int nj = 0; nj < 4; nj++) {                                        \
                    f32x4 z = {};                                                       \
                    z = __builtin_amdgcn_mfma_f32_16x16x32_bf16(kf[nj][0], aq[mf][0], z, 0, 0, 0); \
                    z = __builtin_amdgcn_mfma_f32_16x16x32_bf16(kf[nj][1], aq[mf][1], z, 0, 0, 0); \
                    st[nj] = z;                                                         \
                }                                                                       \
                const bool diag = (tk0 + 64 > f0);                                      \
                float pv[4][4];                                                         \
                _Pragma("unroll")                                                       \
                for (int nj = 0; nj < 4; nj++)                                          \
                    _Pragma("unroll")                                                   \
                    for (int r = 0; r < 4; r++)                                         \
                        pv[nj][r] = exp2f(st[nj][r]);                                   \
                if (diag) {                                                             \
                    _Pragma("unroll")                                                   \
                    for (int nj = 0; nj < 4; nj++) {                                    \
                        const int keyb = tk0 + nj * 16 + quad * 4;                      \
                        _Pragma("unroll")                                               \
                        for (int r = 0; r < 4; r++)                                     \
                            if (keyb + r > qg) pv[nj][r] = 0.f;                         \
                    }                                                                   \
                }                                                                       \
                _Pragma("unroll")                                                       \
                for (int nj = 0; nj < 4; nj++) {                                        \
                    const unsigned int pk0 = __builtin_amdgcn_perm(                     \
                        __float_as_uint(pv[nj][1]), __float_as_uint(pv[nj][0]), 0x07060302u); \
                    const unsigned int pk1 = __builtin_amdgcn_perm(                     \
                        __float_as_uint(pv[nj][3]), __float_as_uint(pv[nj][2]), 0x07060302u); \
                    *(uint2*)&pm[l16 * PST + nj * 16 + quad * 4] = make_uint2(pk0, pk1);\
                }                                                                       \
                __asm volatile("s_waitcnt lgkmcnt(0)" ::: "memory");                    \
                __builtin_amdgcn_s_setprio(1);                                          \
                const s16x8 ap0 = *(const s16x8*)&pm[l16 * PST + quad * 8];             \
                const s16x8 ap1 = *(const s16x8*)&pm[l16 * PST + 32 + quad * 8];        \
                lacc[mf] = __builtin_amdgcn_mfma_f32_16x16x32_bf16(ap0, onesf, lacc[mf], 0, 0, 0); \
                lacc[mf] = __builtin_amdgcn_mfma_f32_16x16x32_bf16(ap1, onesf, lacc[mf], 0, 0, 0); \
                _Pragma("unroll")                                                       \
                for (int ni = 0; ni < 4; ni++) {                                        \
                    yacc[mf][ni] = __builtin_amdgcn_mfma_f32_16x16x32_bf16(ap0, vf[ni][0], yacc[mf][ni], 0, 0, 0); \
                    yacc[mf][ni] = __builtin_amdgcn_mfma_f32_16x16x32_bf16(ap1, vf[ni][1], yacc[mf][ni], 0, 0, 0); \
                }                                                                       \
                __builtin_amdgcn_s_setprio(0);                                          \
            }                                                                           \
        }                                                                               \
    }

    for (int t = 0; t < ntiles; t += 2) {
        ATT_STEP(0, t);
        ATT_STEP(1, t + 1);
    }
#undef ATT_STEP

    // epilogue: lacc[mf][r] is the denominator for q = f0 + quad*4 + r — the exact
    // same (quad,r) indexing as yacc. No cross-lane reduction needed.
    const int bbi = bh >> 4, hh = bh & 15;
    #pragma unroll
    for (int mf = 0; mf < 2; mf++) {
        float linv[4];
        #pragma unroll
        for (int r = 0; r < 4; r++)
            linv[r] = 1.0f / lacc[mf][r];
        #pragma unroll
        for (int ni = 0; ni < 4; ni++)
            #pragma unroll
            for (int r = 0; r < 4; r++) {
                const int trow = q0w + mf * 16 + quad * 4 + r;
                yb[((size_t)bbi * TT + trow) * NE + hh * HD + ni * 16 + l16] =
                    f2bf(yacc[mf][ni][r] * linv[r]);
            }
    }
}

extern "C" void kernel_launch(void* const* d_in, const int* in_sizes, int n_in,
                              void* d_out, int out_size, void* d_ws, size_t ws_size,
                              hipStream_t stream) {
    const float* x      = (const float*)d_in[0];
    const float* ln_w   = (const float*)d_in[1];
    const float* ln_b   = (const float*)d_in[2];
    const float* W_attn = (const float*)d_in[3];
    const float* b_attn = (const float*)d_in[4];
    const float* W_proj = (const float*)d_in[5];
    const float* b_proj = (const float*)d_in[6];
    float* out = (float*)d_out;

    char* ws = (char*)d_ws;
    unsigned short* h    = (unsigned short*)ws;  ws += (size_t)MM * C_IN * 2;
    unsigned short* Wat  = (unsigned short*)ws;  ws += (size_t)N_QKV * C_IN * 2;
    unsigned short* Wpt  = (unsigned short*)ws;  ws += (size_t)NE * NE * 2;
    unsigned short* qbuf = (unsigned short*)ws;  ws += (size_t)MM * NE * 2;
    unsigned short* kbuf = (unsigned short*)ws;  ws += (size_t)MM * NE * 2;
    unsigned short* vtbf = (unsigned short*)ws;  ws += (size_t)MM * NE * 2;
    unsigned short* ybuf = (unsigned short*)ws;  ws += (size_t)MM * NE * 2;

    prep_kernel<<<MM + TCA_BLOCKS + TCP_BLOCKS, 256, 0, stream>>>(x, ln_w, ln_b, h,
                                                                  W_attn, Wat, W_proj, Wpt);
    gemm_bt<0><<<dim3(N_QKV / 128, MM / 128), 256, 0, stream>>>(h, Wat, b_attn, qbuf, kbuf, vtbf,
                                                                MM, N_QKV, C_IN);
    attn_kernel<<<64 * 16, 256, 0, stream>>>(qbuf, kbuf, vtbf, ybuf);
    gemm_bt<1><<<dim3(NE / 128, MM / 128), 256, 0, stream>>>(ybuf, Wpt, b_proj, out, nullptr, nullptr,
                                                             MM, NE, NE);
}

// Round 12
// 284.134 us; speedup vs baseline: 1.0242x; 1.0242x over previous
//
#include <hip/hip_runtime.h>
#include <hip/hip_bf16.h>

// ---- constants for this problem ----
#define BB 4
#define TT 2048
#define C_IN 1152
#define NE 1024
#define NH 16
#define HD 64
#define MM (BB*TT)          // 8192
#define N_QKV (3*NE)        // 3072

typedef __attribute__((ext_vector_type(8))) short s16x8;
typedef __attribute__((ext_vector_type(4))) short s16x4;
typedef __attribute__((ext_vector_type(4))) float f32x4;

static __device__ __forceinline__ unsigned short f2bf(float x) {
    unsigned int u = __float_as_uint(x);
    unsigned int r = (u + 0x7fffu + ((u >> 16) & 1u)) >> 16;
    return (unsigned short)r;
}

// async global->LDS, 16 B per lane. LDS dest = wave-uniform base + lane*16.
static __device__ __forceinline__ void async16(const void* g, void* l) {
    __builtin_amdgcn_global_load_lds((const __attribute__((address_space(1))) void*)g,
                                     (__attribute__((address_space(3))) void*)l, 16, 0, 0);
}

// ---- prep kernel: LN (blocks 0..MM-1) + both weight transposes (rest) ----
#define TCA_BLOCKS ((N_QKV / 32) * (C_IN / 32))   /* 3456 */
#define TCP_BLOCKS ((NE / 32) * (NE / 32))        /* 1024 */
__global__ __launch_bounds__(256) void prep_kernel(const float* __restrict__ x,
                                                   const float* __restrict__ lw,
                                                   const float* __restrict__ lb,
                                                   unsigned short* __restrict__ h,
                                                   const float* __restrict__ Wa,
                                                   unsigned short* __restrict__ Wat,
                                                   const float* __restrict__ Wp,
                                                   unsigned short* __restrict__ Wpt) {
    __shared__ float tile[32][33];
    __shared__ float red[2][4];
    const int bid = blockIdx.x;
    const int tid = threadIdx.x;

    if (bid < MM) {
        // ---- LayerNorm row (float4 loads, registers kept, bf16x4 stores) ----
        const float4* xr = (const float4*)(x + (size_t)bid * C_IN);   // 288 float4
        const float4 a0 = xr[tid];
        float4 a1 = make_float4(0.f, 0.f, 0.f, 0.f);
        if (tid < 32) a1 = xr[256 + tid];
        float s  = a0.x + a0.y + a0.z + a0.w + a1.x + a1.y + a1.z + a1.w;
        float sq = a0.x*a0.x + a0.y*a0.y + a0.z*a0.z + a0.w*a0.w
                 + a1.x*a1.x + a1.y*a1.y + a1.z*a1.z + a1.w*a1.w;
        for (int off = 1; off < 64; off <<= 1) {
            s  += __shfl_xor(s, off, 64);
            sq += __shfl_xor(sq, off, 64);
        }
        const int wid = tid >> 6, lane = tid & 63;
        if (lane == 0) { red[0][wid] = s; red[1][wid] = sq; }
        __syncthreads();
        s  = red[0][0] + red[0][1] + red[0][2] + red[0][3];
        sq = red[1][0] + red[1][1] + red[1][2] + red[1][3];
        const float mu  = s * (1.f / C_IN);
        const float var = sq * (1.f / C_IN) - mu * mu;
        const float rs  = rsqrtf(var + 1e-5f);
        const float4* w4 = (const float4*)lw;
        const float4* b4 = (const float4*)lb;
        unsigned short* hr = h + (size_t)bid * C_IN;
        {
            const float4 wv = w4[tid], bv = b4[tid];
            s16x4 o;
            o[0] = (short)f2bf((a0.x - mu) * rs * wv.x + bv.x);
            o[1] = (short)f2bf((a0.y - mu) * rs * wv.y + bv.y);
            o[2] = (short)f2bf((a0.z - mu) * rs * wv.z + bv.z);
            o[3] = (short)f2bf((a0.w - mu) * rs * wv.w + bv.w);
            *(s16x4*)(hr + tid * 4) = o;
        }
        if (tid < 32) {
            const float4 wv = w4[256 + tid], bv = b4[256 + tid];
            s16x4 o;
            o[0] = (short)f2bf((a1.x - mu) * rs * wv.x + bv.x);
            o[1] = (short)f2bf((a1.y - mu) * rs * wv.y + bv.y);
            o[2] = (short)f2bf((a1.z - mu) * rs * wv.z + bv.z);
            o[3] = (short)f2bf((a1.w - mu) * rs * wv.w + bv.w);
            *(s16x4*)(hr + (256 + tid) * 4) = o;
        }
        return;
    }

    // ---- transpose+cast tile ----
    const float* in; unsigned short* out; int K, N, n0, k0;
    if (bid < MM + TCA_BLOCKS) {
        const int idx = bid - MM;
        in = Wa; out = Wat; K = C_IN; N = N_QKV;
        n0 = (idx % (N_QKV / 32)) * 32; k0 = (idx / (N_QKV / 32)) * 32;
    } else {
        const int idx = bid - MM - TCA_BLOCKS;
        in = Wp; out = Wpt; K = NE; N = NE;
        n0 = (idx % (NE / 32)) * 32; k0 = (idx / (NE / 32)) * 32;
    }
    const int tx = tid & 31, ty = tid >> 5;   // 32 x 8
    for (int i = ty; i < 32; i += 8)
        tile[i][tx] = in[(size_t)(k0 + i) * N + n0 + tx];
    __syncthreads();
    for (int i = ty; i < 32; i += 8)
        out[(size_t)(n0 + i) * K + k0 + tx] = f2bf(tile[tx][i]);
}

#define ATT_SC 0.18033688011112042f   /* (1/8) * log2(e) */

// ------------- GEMM: A bf16 [M][K] x Bt bf16 [N][K] + bias -> epilogue -------------
// Round-8 proven K-loop: BK=64, XOR-swizzled 128-B LDS rows.
// Round-9: MODE-0 L2-local 2D sub-tiled work order; single-stage MODE-0 epilogue.
// Round-12: MODE 1 tile 128x64 (BN=64): grid 512->1024 blocks, LDS 64->48 KB ->
//   3 blocks/CU (was 2). gemm1 was the one never-profiled cell; its small-grid
//   2-block residency is the latency-bound suspect. B-reuse loss irrelevant
//   (Wpt = 2 MB, L2-resident).
#define EP_STRIDE 136   /* ushort; 272 B rows keep 16 B alignment for b128 */
template <int MODE>
__global__ __launch_bounds__(256) void gemm_bt(const unsigned short* __restrict__ A,
                                               const unsigned short* __restrict__ Bt,
                                               const float* __restrict__ bias,
                                               void* __restrict__ outp,
                                               unsigned short* __restrict__ kb,
                                               unsigned short* __restrict__ vt,
                                               int M, int N, int K) {
    constexpr int BN   = (MODE == 0) ? 128 : 64;
    constexpr int NB   = BN / 32;            // n-frags per wave: 4 or 2
    constexpr int ABUF = 8192;               // shorts per A k-tile buffer (16 KB)
    constexpr int BBUF = BN * 64;            // shorts per B k-tile buffer
    constexpr int BUFS = ABUF + BBUF;
    __shared__ unsigned short smem[2 * BUFS];   // 64 KB (MODE0) / 48 KB (MODE1)
    const int tid = threadIdx.x;
    const int wid = tid >> 6, lane = tid & 63;
    const int wm = wid >> 1, wn = wid & 1;
    const int quad = lane >> 4, l16 = lane & 15;

    int m0, n0;
    if (MODE == 0) {
        // 2D sub-tiled XCD-local order: grid (24,64)=1536, 192 wg per XCD.
        const int bid = blockIdx.y * gridDim.x + blockIdx.x;
        const int xcd = bid & 7;
        const int k   = bid >> 3;          // 0..191
        const int mg  = k / 96;            // 0..1
        const int r1  = k % 96;
        const int ng  = r1 / 32;           // 0..2
        const int rr  = r1 % 32;
        m0 = (xcd * 8 + mg * 4 + (rr & 3)) * 128;
        n0 = (ng * 8 + (rr >> 2)) * 128;
    } else {
        // T1 bijective XCD-chunked swizzle (nwg % 8 == 0)
        const int gx  = gridDim.x;
        const int nwg = gx * gridDim.y;
        const int bid = blockIdx.y * gx + blockIdx.x;
        const int wg  = (bid & 7) * (nwg >> 3) + (bid >> 3);
        m0 = (wg / gx) * 128; n0 = (wg % gx) * BN;
    }

    // staging: 8 lanes per row, chunk sc XOR'd by row&7 (128-B window -> coalesced)
    const int rl = lane >> 3;                     // 0..7
    const int sc = (lane & 7) ^ rl;               // stored chunk index
    const int bwid = (MODE == 0) ? wid : (wid & 1);   // B staged by waves 0-1 in MODE1
    const unsigned short* gA = A  + (size_t)(m0 + wid * 32 + rl) * K + sc * 8;
    const unsigned short* gB = Bt + (size_t)(n0 + bwid * 32 + rl) * K + sc * 8;

    f32x4 acc[4][NB] = {};
    const int nk = K >> 6;

    // per-thread read chunk indices (inverse XOR): row&7 == l16&7 for all frags
    const int sc0 = (quad ^ (l16 & 7)) * 8;
    const int sc1 = ((4 + quad) ^ (l16 & 7)) * 8;

#define STAGE(KT, BUF)                                                          \
    {                                                                           \
        const unsigned short* a_ = gA + (KT) * 64;                              \
        unsigned short* sa_ = &smem[(BUF) * BUFS + wid * 2048];                 \
        _Pragma("unroll")                                                       \
        for (int j = 0; j < 4; j++)                                             \
            async16(a_ + (size_t)(j * 8) * K, sa_ + j * 512);                   \
        if (MODE == 0 || wid < 2) {                                             \
            const unsigned short* b_ = gB + (KT) * 64;                          \
            unsigned short* sb_ = &smem[(BUF) * BUFS + ABUF + wid * 2048];      \
            _Pragma("unroll")                                                   \
            for (int j = 0; j < 4; j++)                                         \
                async16(b_ + (size_t)(j * 8) * K, sb_ + j * 512);               \
        }                                                                       \
    }

    STAGE(0, 0);

    for (int kt = 0; kt < nk; kt++) {
        __syncthreads();
        const int cur = kt & 1;
        if (kt + 1 < nk) STAGE(kt + 1, cur ^ 1);

        const unsigned short* As_ = &smem[cur * BUFS];
        const unsigned short* Bs_ = &smem[cur * BUFS + ABUF];
        #pragma unroll
        for (int h = 0; h < 2; h++) {
            const int sch = h ? sc1 : sc0;
            s16x8 af[4], bfb[NB];
            #pragma unroll
            for (int mi = 0; mi < 4; mi++)
                af[mi] = *(const s16x8*)&As_[(wm * 64 + mi * 16 + l16) * 64 + sch];
            #pragma unroll
            for (int ni = 0; ni < NB; ni++)
                bfb[ni] = *(const s16x8*)&Bs_[(wn * (BN / 2) + ni * 16 + l16) * 64 + sch];
            #pragma unroll
            for (int mi = 0; mi < 4; mi++)
                #pragma unroll
                for (int ni = 0; ni < NB; ni++)
                    acc[mi][ni] = __builtin_amdgcn_mfma_f32_16x16x32_bf16(af[mi], bfb[ni], acc[mi][ni], 0, 0, 0);
        }
    }
#undef STAGE

    const int which0 = n0 >> 10;
    const float sc_ = (MODE == 0 && which0 == 0) ? ATT_SC : 1.0f;
    for (int ni = 0; ni < NB; ni++) {
        const float bv = bias[n0 + wn * (BN / 2) + ni * 16 + l16];
        for (int mi = 0; mi < 4; mi++)
            for (int r = 0; r < 4; r++)
                acc[mi][ni][r] = (acc[mi][ni][r] + bv) * sc_;
    }

    if (MODE == 1) {
        // LDS-routed coalesced fp32 epilogue: 2 passes of 64 rows, Tf [64][BN=64].
        float* Tf = (float*)smem;
        float* out = (float*)outp;
        for (int p = 0; p < 2; p++) {
            __syncthreads();
            if (wm == p) {
                for (int mi = 0; mi < 4; mi++)
                    for (int ni = 0; ni < NB; ni++) {
                        const int col = wn * (BN / 2) + ni * 16 + l16;
                        for (int r = 0; r < 4; r++)
                            Tf[(mi * 16 + quad * 4 + r) * BN + col] = acc[mi][ni][r];
                    }
            }
            __syncthreads();
            const int rlo = tid >> 4;         // 0..15 (16 float4 per 64-col row)
            const int c4 = (tid & 15) * 4;    // f32 col, 16B-aligned
            for (int rr2 = rlo; rr2 < 64; rr2 += 16) {
                *(float4*)&out[(size_t)(m0 + p * 64 + rr2) * N + n0 + c4] =
                    *(const float4*)&Tf[rr2 * BN + c4];
            }
        }
        return;
    }

    // ---- MODE 0: single-stage LDS-routed epilogue (T [128][EP_STRIDE]) ----
    const int which = n0 >> 10;
    const int bb = m0 >> 11;
    const int mloc = m0 & 2047;
    unsigned short* T = smem;

    __syncthreads();
    if (which < 2) {
        for (int mi = 0; mi < 4; mi++)
            for (int ni = 0; ni < 4; ni++) {
                const int nl = wn * 64 + ni * 16 + l16;
                for (int r = 0; r < 4; r++)
                    T[(wm * 64 + mi * 16 + quad * 4 + r) * EP_STRIDE + nl] = f2bf(acc[mi][ni][r]);
            }
    } else {
        for (int mi = 0; mi < 4; mi++)
            for (int ni = 0; ni < 4; ni++) {
                const int nlh = wn * 64 + ni * 16 + l16;
                const int mlb = wm * 64 + mi * 16 + quad * 4;
                for (int r = 0; r < 4; r += 2) {
                    const unsigned int pk = (unsigned int)f2bf(acc[mi][ni][r]) |
                                            ((unsigned int)f2bf(acc[mi][ni][r + 1]) << 16);
                    *(unsigned int*)&T[nlh * EP_STRIDE + mlb + r] = pk;
                }
            }
    }
    __syncthreads();

    if (which < 2) {
        unsigned short* qk = (which == 0) ? (unsigned short*)outp : kb;
        const int ml = tid >> 2, c = tid & 3;
        const int nl0 = c * 32;
        const int hh = ((n0 & 1023) >> 6) + (nl0 >> 6);
        const int d0 = nl0 & 63;
        for (int half = 0; half < 2; half++) {
            const int row = half * 64 + ml;
            const int t = mloc + row;
            unsigned short* dst = qk + ((size_t)(bb * 16 + hh) * TT + t) * HD + d0;
            const unsigned short* src = &T[row * EP_STRIDE + nl0];
            for (int u = 0; u < 4; u++)
                *(s16x8*)(dst + u * 8) = *(const s16x8*)(src + u * 8);
        }
    } else {
        const int nlh = tid >> 2, c = tid & 3;
        const int hb = (n0 - 2048) >> 6;
        for (int half = 0; half < 2; half++) {
            const int row = half * 64 + nlh;
            unsigned short* dst = vt + ((size_t)(bb * 16 + hb + half) * HD + nlh) * TT + mloc + c * 32;
            const unsigned short* src = &T[row * EP_STRIDE + c * 32];
            for (int u = 0; u < 4; u++)
                *(s16x8*)(dst + u * 8) = *(const s16x8*)(src + u * 8);
        }
    }
}

// ------------- flash attention: S^T trick + ones-MFMA row sums -------------
// Round-9 proven version (best measured: 81.4 us): 4-wave 256-thread blocks,
// round-0 schedule (2-buffer __syncthreads staging, XOR-swizzled K/V),
// diag-hoisted causal mask, setprio(1) around the rowsum+PV MFMA cluster.
#define PST 72                         /* shorts; 144 B rows, 16B-aligned */

__global__ __launch_bounds__(256) void attn_kernel(const unsigned short* __restrict__ qb,
                                                   const unsigned short* __restrict__ kb,
                                                   const unsigned short* __restrict__ vt,
                                                   unsigned short* __restrict__ yb) {
    __shared__ unsigned short Ks[2][64 * 64];
    __shared__ unsigned short Vs[2][64 * 64];
    __shared__ unsigned short Ps[4][2 * 16 * PST];   // per-wave, per-mf [16 q][PST]
    const int tid = threadIdx.x, wid = tid >> 6, lane = tid & 63;
    const int quad = lane >> 4, l16 = lane & 15;
    const int bh = blockIdx.x & 63;
    const int qblk = 15 - (blockIdx.x >> 6);         // longest-first (LPT packing)

    const unsigned short* qh = qb + (size_t)bh * TT * HD;
    const unsigned short* kh = kb + (size_t)bh * TT * HD;
    const unsigned short* vh = vt + (size_t)bh * HD * TT;
    unsigned short* ps = Ps[wid];

    const int q0w = qblk * 128 + wid * 32;           // this wave's 32 q-rows
    s16x8 aq[2][2];
    #pragma unroll
    for (int mf = 0; mf < 2; mf++) {
        aq[mf][0] = *(const s16x8*)&qh[(size_t)(q0w + mf * 16 + l16) * HD + quad * 8];
        aq[mf][1] = *(const s16x8*)&qh[(size_t)(q0w + mf * 16 + l16) * HD + 32 + quad * 8];
    }
    // ones B-frag (bf16 1.0 = 0x3F80)
    s16x8 onesf;
    #pragma unroll
    for (int i = 0; i < 8; i++) onesf[i] = (short)0x3F80;

    f32x4 yacc[2][4] = {};
    f32x4 lacc[2] = {};                              // row-sum accumulators
    const int ntiles = 2 * qblk + 2;                 // always even

    // staging: row r = wid*16 + {0,8} + rl, chunk cc XOR-swizzled; pointers bumped
    const int rl = lane >> 3;
    const int cc = (lane & 7) ^ (rl & 7);
    const unsigned short* kp0 = kh + (size_t)(wid * 16 + rl) * HD + cc * 8;
    const unsigned short* kp1 = kh + (size_t)(wid * 16 + 8 + rl) * HD + cc * 8;
    const unsigned short* vp0 = vh + (size_t)(wid * 16 + rl) * TT + cc * 8;
    const unsigned short* vp1 = vh + (size_t)(wid * 16 + 8 + rl) * TT + cc * 8;
    const int ldsK0 = wid * 16 * 64, ldsK1 = (wid * 16 + 8) * 64;

    // prologue: stage tile 0 into buffer 0; bump to tile 1
    async16(kp0, &Ks[0][ldsK0]);  async16(kp1, &Ks[0][ldsK1]);
    async16(vp0, &Vs[0][ldsK0]);  async16(vp1, &Vs[0][ldsK1]);
    kp0 += 64 * HD; kp1 += 64 * HD; vp0 += 64; vp1 += 64;

    const int p0s = quad ^ (l16 & 7);
    const int p1s = (4 + quad) ^ (l16 & 7);

#define ATT_STEP(CUR, TT_)                                                              \
    {                                                                                   \
        __syncthreads();                                                                \
        if ((TT_) + 1 < ntiles) {                                                       \
            async16(kp0, &Ks[(CUR) ^ 1][ldsK0]);  async16(kp1, &Ks[(CUR) ^ 1][ldsK1]);  \
            async16(vp0, &Vs[(CUR) ^ 1][ldsK0]);  async16(vp1, &Vs[(CUR) ^ 1][ldsK1]);  \
            kp0 += 64 * HD; kp1 += 64 * HD; vp0 += 64; vp1 += 64;                       \
        }                                                                               \
        const int tk0 = (TT_) * 64;                                                     \
        if (tk0 <= q0w + 31) {                                                          \
            const unsigned short* Kc = Ks[CUR];                                         \
            const unsigned short* Vc = Vs[CUR];                                         \
            s16x8 kf[4][2], vf[4][2];                                                   \
            _Pragma("unroll")                                                           \
            for (int nj = 0; nj < 4; nj++) {                                            \
                kf[nj][0] = *(const s16x8*)&Kc[(nj * 16 + l16) * 64 + p0s * 8];         \
                kf[nj][1] = *(const s16x8*)&Kc[(nj * 16 + l16) * 64 + p1s * 8];         \
            }                                                                           \
            _Pragma("unroll")                                                           \
            for (int ni = 0; ni < 4; ni++) {                                            \
                vf[ni][0] = *(const s16x8*)&Vc[(ni * 16 + l16) * 64 + p0s * 8];         \
                vf[ni][1] = *(const s16x8*)&Vc[(ni * 16 + l16) * 64 + p1s * 8];         \
            }                                                                           \
            _Pragma("unroll")                                                           \
            for (int mf = 0; mf < 2; mf++) {                                            \
                const int f0 = q0w + mf * 16;                                           \
                if (tk0 > f0 + 15) continue;                                            \
                unsigned short* pm = ps + mf * (16 * PST);                              \
                const int qg = f0 + l16;                                                \
                f32x4 st[4];                                                            \
                _Pragma("unroll")                                                       \
                for (int nj = 0; nj < 4; nj++) {                                        \
                    f32x4 z = {};                                                       \
                    z = __builtin_amdgcn_mfma_f32_16x16x32_bf16(kf[nj][0], aq[mf][0], z, 0, 0, 0); \
                    z = __builtin_amdgcn_mfma_f32_16x16x32_bf16(kf[nj][1], aq[mf][1], z, 0, 0, 0); \
                    st[nj] = z;                                                         \
                }                                                                       \
                const bool diag = (tk0 + 64 > f0);                                      \
                float pv[4][4];                                                         \
                _Pragma("unroll")                                                       \
                for (int nj = 0; nj < 4; nj++)                                          \
                    _Pragma("unroll")                                                   \
                    for (int r = 0; r < 4; r++)                                         \
                        pv[nj][r] = exp2f(st[nj][r]);                                   \
                if (diag) {                                                             \
                    _Pragma("unroll")                                                   \
                    for (int nj = 0; nj < 4; nj++) {                                    \
                        const int keyb = tk0 + nj * 16 + quad * 4;                      \
                        _Pragma("unroll")                                               \
                        for (int r = 0; r < 4; r++)                                     \
                            if (keyb + r > qg) pv[nj][r] = 0.f;                         \
                    }                                                                   \
                }                                                                       \
                _Pragma("unroll")                                                       \
                for (int nj = 0; nj < 4; nj++) {                                        \
                    const unsigned int pk0 = __builtin_amdgcn_perm(                     \
                        __float_as_uint(pv[nj][1]), __float_as_uint(pv[nj][0]), 0x07060302u); \
                    const unsigned int pk1 = __builtin_amdgcn_perm(                     \
                        __float_as_uint(pv[nj][3]), __float_as_uint(pv[nj][2]), 0x07060302u); \
                    *(uint2*)&pm[l16 * PST + nj * 16 + quad * 4] = make_uint2(pk0, pk1);\
                }                                                                       \
                __asm volatile("s_waitcnt lgkmcnt(0)" ::: "memory");                    \
                __builtin_amdgcn_s_setprio(1);                                          \
                const s16x8 ap0 = *(const s16x8*)&pm[l16 * PST + quad * 8];             \
                const s16x8 ap1 = *(const s16x8*)&pm[l16 * PST + 32 + quad * 8];        \
                lacc[mf] = __builtin_amdgcn_mfma_f32_16x16x32_bf16(ap0, onesf, lacc[mf], 0, 0, 0); \
                lacc[mf] = __builtin_amdgcn_mfma_f32_16x16x32_bf16(ap1, onesf, lacc[mf], 0, 0, 0); \
                _Pragma("unroll")                                                       \
                for (int ni = 0; ni < 4; ni++) {                                        \
                    yacc[mf][ni] = __builtin_amdgcn_mfma_f32_16x16x32_bf16(ap0, vf[ni][0], yacc[mf][ni], 0, 0, 0); \
                    yacc[mf][ni] = __builtin_amdgcn_mfma_f32_16x16x32_bf16(ap1, vf[ni][1], yacc[mf][ni], 0, 0, 0); \
                }                                                                       \
                __builtin_amdgcn_s_setprio(0);                                          \
            }                                                                           \
        }                                                                               \
    }

    for (int t = 0; t < ntiles; t += 2) {
        ATT_STEP(0, t);
        ATT_STEP(1, t + 1);
    }
#undef ATT_STEP

    // epilogue: lacc[mf][r] is the denominator for q = f0 + quad*4 + r — the exact
    // same (quad,r) indexing as yacc. No cross-lane reduction needed.
    const int bbi = bh >> 4, hh = bh & 15;
    #pragma unroll
    for (int mf = 0; mf < 2; mf++) {
        float linv[4];
        #pragma unroll
        for (int r = 0; r < 4; r++)
            linv[r] = 1.0f / lacc[mf][r];
        #pragma unroll
        for (int ni = 0; ni < 4; ni++)
            #pragma unroll
            for (int r = 0; r < 4; r++) {
                const int trow = q0w + mf * 16 + quad * 4 + r;
                yb[((size_t)bbi * TT + trow) * NE + hh * HD + ni * 16 + l16] =
                    f2bf(yacc[mf][ni][r] * linv[r]);
            }
    }
}

extern "C" void kernel_launch(void* const* d_in, const int* in_sizes, int n_in,
                              void* d_out, int out_size, void* d_ws, size_t ws_size,
                              hipStream_t stream) {
    const float* x      = (const float*)d_in[0];
    const float* ln_w   = (const float*)d_in[1];
    const float* ln_b   = (const float*)d_in[2];
    const float* W_attn = (const float*)d_in[3];
    const float* b_attn = (const float*)d_in[4];
    const float* W_proj = (const float*)d_in[5];
    const float* b_proj = (const float*)d_in[6];
    float* out = (float*)d_out;

    char* ws = (char*)d_ws;
    unsigned short* h    = (unsigned short*)ws;  ws += (size_t)MM * C_IN * 2;
    unsigned short* Wat  = (unsigned short*)ws;  ws += (size_t)N_QKV * C_IN * 2;
    unsigned short* Wpt  = (unsigned short*)ws;  ws += (size_t)NE * NE * 2;
    unsigned short* qbuf = (unsigned short*)ws;  ws += (size_t)MM * NE * 2;
    unsigned short* kbuf = (unsigned short*)ws;  ws += (size_t)MM * NE * 2;
    unsigned short* vtbf = (unsigned short*)ws;  ws += (size_t)MM * NE * 2;
    unsigned short* ybuf = (unsigned short*)ws;  ws += (size_t)MM * NE * 2;

    prep_kernel<<<MM + TCA_BLOCKS + TCP_BLOCKS, 256, 0, stream>>>(x, ln_w, ln_b, h,
                                                                  W_attn, Wat, W_proj, Wpt);
    gemm_bt<0><<<dim3(N_QKV / 128, MM / 128), 256, 0, stream>>>(h, Wat, b_attn, qbuf, kbuf, vtbf,
                                                                MM, N_QKV, C_IN);
    attn_kernel<<<64 * 16, 256, 0, stream>>>(qbuf, kbuf, vtbf, ybuf);
    gemm_bt<1><<<dim3(NE / 64, MM / 128), 256, 0, stream>>>(ybuf, Wpt, b_proj, out, nullptr, nullptr,
                                                            MM, NE, NE);
}